// Round 3
// baseline (102.046 us; speedup 1.0000x reference)
//
#include <hip/hip_runtime.h>

// Problem dims (from reference setup_inputs)
#define BB 4
#define CC 64
#define HH 256
#define WW 256
#define NPIX (HH*WW)          // 65536
#define NCLS 4
#define NPAIR 12              // B*(NCLS-1)
#define HALF 512
#define MAXS 1024
#define NOUT (NPAIR*CC*MAXS)  // 786432
#define NBAND 128             // 2-row bands per image (was 64x 4-row)
#define BANDCAP 512           // max class pixels per 2-row band

// ---------------------------------------------------------------------------
// Round 8: same 2-kernel structure (r7 = 102.0us). Two latency fixes:
//  K1: 2-row bands -> 512 blocks = 2 blocks/CU, 8 waves/CU (was 1 block/CU,
//      4 waves/CU with zero TLP slack across syncthreads phases). Costs
//      +2.1MB halo re-read of preds (~+0.33us BW) for 2x latency hiding.
//  K3: the 6-step binary search (6 DEPENDENT LDS reads ~700cy/thread) is
//      replaced by an inverted LDS table: the 128 band-threads scatter
//      slot->(flag|band|rankBase) entries for this block's 256-slot quarter;
//      each thread then does ONE LDS read -> bucket read -> feat gather.
// Slot arithmetic/validity intervals identical to the verified kernel.
// The 2x ~41.3us 256MiB poison fills (81% HBM peak, rocprof top-5) are
// harness-fixed; controllable remainder ~19.5us incl ~5us launch overhead.
// ---------------------------------------------------------------------------

// K1: fused argmax + separable 3x3 dilation + per-band bucket compaction.
// Block = one 2-row x 256-col band. Vertical 3-max in registers (4 halo rows),
// horizontal 3-max via LDS. Per row: 6 ballots (3 classes x hard/easy);
// per-wave popcounts -> LDS; 48-thread exclusive prefix over (row, wave);
// each flagged pixel writes its pixel index at its in-band rank (raster order
// preserved: rows -> waves -> lanes). Per-band totals packed hard|easy<<16.
// OOB halo rows use argmax=0 (safe: window always contains the center pixel).
__global__ void __launch_bounds__(256) k_count(
        const float* __restrict__ preds, const int* __restrict__ labels,
        int* __restrict__ hardBuf, int* __restrict__ easyBuf,
        unsigned* __restrict__ bandCounts) {
    __shared__ unsigned char vm[2][WW];
    __shared__ unsigned short cnt[48];   // [(cls,typ)=c2][ry(2)][w(4)] = c2*8+ry*4+w
    __shared__ unsigned short pre[48];   // exclusive prefix over (ry,w) per c2
    int bx = blockIdx.x;
    int b = bx >> 7, band = bx & 127;
    int y0 = band * 2;
    int x = threadIdx.x;
    const float* pb = preds + (size_t)b * NCLS * NPIX;

    unsigned char am[4];
#pragma unroll
    for (int r = 0; r < 4; ++r) {
        int y = y0 + r - 1;
        unsigned char a = 0;
        if (y >= 0 && y < HH) {
            const float* p = pb + y * WW + x;
            float best = p[0];
            int arg = 0;
#pragma unroll
            for (int c = 1; c < NCLS; ++c) {
                float v = p[(size_t)c * NPIX];
                if (v > best) { best = v; arg = c; }   // first-max wins (jnp.argmax)
            }
            a = (unsigned char)arg;
        }
        am[r] = a;
    }
    unsigned char vmr[2];
#pragma unroll
    for (int ry = 0; ry < 2; ++ry) {
        int m = am[ry];
        if (am[ry + 1] > m) m = am[ry + 1];
        if (am[ry + 2] > m) m = am[ry + 2];
        vmr[ry] = (unsigned char)m;
        vm[ry][x] = (unsigned char)m;
    }
    __syncthreads();

    int lane = x & 63, w = x >> 6;
    unsigned long long lt = (1ull << lane) - 1ull;   // lanemask_lt (lane<64 ok)

    int pos[2], cls2[2], typ2[2];
#pragma unroll
    for (int ry = 0; ry < 2; ++ry) {
        int m = vmr[ry];
        if (x > 0)      { int v = vm[ry][x - 1]; if (v > m) m = v; }
        if (x < WW - 1) { int v = vm[ry][x + 1]; if (v > m) m = v; }
        int l = labels[b * NPIX + (y0 + ry) * WW + x];
        cls2[ry] = l - 1;                 // -1 for ignore label 0
        typ2[ry] = (m == l) ? 1 : 0;      // 1 = easy, 0 = hard
        int p = 0;
#pragma unroll
        for (int c = 1; c <= 3; ++c) {
            unsigned long long hm = __ballot(l == c && m != c);
            unsigned long long em = __ballot(l == c && m == c);
            if (lane == 0) {
                cnt[((c - 1) * 2 + 0) * 8 + ry * 4 + w] = (unsigned short)__popcll(hm);
                cnt[((c - 1) * 2 + 1) * 8 + ry * 4 + w] = (unsigned short)__popcll(em);
            }
            if (l == c) p = (int)__popcll(((m != c) ? hm : em) & lt);
        }
        pos[ry] = p;
    }
    __syncthreads();

    if (x < 48) {                         // c2 = x>>3, k = x&7 over (ry,w)
        int base = x & ~7, k = x & 7;
        int s = 0;
        for (int j = 0; j < k; ++j) s += cnt[base + j];
        pre[x] = (unsigned short)s;
    }
    __syncthreads();

    if (x < 3) {                          // per-band totals, hard | easy<<16
        int th = pre[(x * 2 + 0) * 8 + 7] + cnt[(x * 2 + 0) * 8 + 7];
        int te = pre[(x * 2 + 1) * 8 + 7] + cnt[(x * 2 + 1) * 8 + 7];
        bandCounts[(b * 3 + x) * NBAND + band] = (unsigned)th | ((unsigned)te << 16);
    }
#pragma unroll
    for (int ry = 0; ry < 2; ++ry) {
        int cc = cls2[ry];
        if (cc >= 0) {
            int c2 = cc * 2 + typ2[ry];
            int r = pre[c2 * 8 + ry * 4 + w] + pos[ry];       // in-band rank
            int pair = b * 3 + cc;
            int* buf = typ2[ry] ? easyBuf : hardBuf;
            buf[(((pair << 7) | band) << 9) + r] = (y0 + ry) * WW + x;
        }
    }
}

// K3: gather. Block = one (pair, channel, slot-quarter): 3072 blocks,
// 1 slot/thread, 8 resident blocks/CU. Threads 0..127 (2 waves) scan the
// pair's 128 packed band counts into cumH/cumE; the same threads then
// SCATTER an inverted LDS table for this block's 256-slot quarter:
// tbl[slot-qlo] = easyFlag<<31 | band<<16 | rankBase (rankBase = cumH[band]
// for hard, easyStart+cumE[band] for easy; regions provably disjoint:
// easyStart = max(Nh,512) >= hardEnd). Each thread: ONE LDS read ->
// bucket read (L2-hot, shared by the pair's 256 blocks) -> feat gather ->
// coalesced store. Invalid slots keep 0xffffffff (band=255 impossible) -> 0.
// Buckets need no init: rank < per-band count always.
__global__ void __launch_bounds__(256) k_gather(
        const float* __restrict__ feat, const int* __restrict__ hardBuf,
        const int* __restrict__ easyBuf, const unsigned* __restrict__ bandCounts,
        float* __restrict__ out) {
    __shared__ int cumH[NBAND + 1], cumE[NBAND + 1];
    __shared__ int wtotH, wtotE;
    __shared__ unsigned tbl[256];
    int blk = blockIdx.x;
    int pc = blk >> 2;                     // pair*CC + c
    int q = blk & 3;                       // slot quarter
    int pair = pc >> 6, c = pc & 63;
    int t = threadIdx.x;
    int lane = t & 63;

    tbl[t] = 0xffffffffu;
    int hv = 0, ev = 0;
    if (t < NBAND) {                       // 2-wave inclusive scan of 128 bands
        unsigned v = bandCounts[pair * NBAND + t];
        hv = (int)(v & 0xffffu); ev = (int)(v >> 16);
#pragma unroll
        for (int off = 1; off < 64; off <<= 1) {
            int hu = __shfl_up(hv, off, 64);
            int eu = __shfl_up(ev, off, 64);
            if (lane >= off) { hv += hu; ev += eu; }
        }
        if (t == 63) { wtotH = hv; wtotE = ev; }
    }
    __syncthreads();
    if (t < NBAND) {
        if (t >= 64) { hv += wtotH; ev += wtotE; }
        cumH[t + 1] = hv;
        cumE[t + 1] = ev;
        if (t == 0) { cumH[0] = 0; cumE[0] = 0; }
    }
    __syncthreads();

    int Nh = cumH[NBAND], Ne = cumE[NBAND];
    int excess = Nh - HALF; if (excess < 0) excess = 0;
    int hardEnd = Nh < MAXS ? Nh : MAXS;
    int easyStart = HALF + excess;
    int easyEnd = easyStart + Ne; if (easyEnd > MAXS) easyEnd = MAXS;
    if (c == 0 && q == 0 && t == 0)
        out[NOUT + pair] = (float)(pair % 3 + 1);            // feat_label

    int qlo = q * 256, qhi = qlo + 256;
    if (t < NBAND) {                       // scatter inverted slot->band table
        // hard: band t owns slots [cumH[t], cumH[t+1]) within [0, hardEnd)
        int s0 = cumH[t], s1 = cumH[t + 1];
        if (s1 > hardEnd) s1 = hardEnd;
        if (s0 < qlo) s0 = qlo;
        if (s1 > qhi) s1 = qhi;
        unsigned entH = ((unsigned)t << 16) | (unsigned)cumH[t];
        for (int s = s0; s < s1; ++s) tbl[s - qlo] = entH;
        // easy: band t owns slots [easyStart+cumE[t], easyStart+cumE[t+1])
        int e0 = easyStart + cumE[t], e1 = easyStart + cumE[t + 1];
        if (e1 > easyEnd) e1 = easyEnd;
        if (e0 < qlo) e0 = qlo;
        if (e1 > qhi) e1 = qhi;
        unsigned entE = 0x80000000u | ((unsigned)t << 16) |
                        (unsigned)(easyStart + cumE[t]);
        for (int s = e0; s < e1; ++s) tbl[s - qlo] = entE;
    }
    __syncthreads();

    int b = pair / 3;
    const float* fp = feat + (size_t)(b * CC + c) * NPIX;
    unsigned ent = tbl[t];
    float val = 0.0f;
    if (ent != 0xffffffffu) {
        int band = (int)((ent >> 16) & 0xffu);
        int off = (qlo + t) - (int)(ent & 0xffffu);
        const int* buf = (ent & 0x80000000u) ? easyBuf : hardBuf;
        int pix = buf[(((pair << 7) | band) << 9) + off];
        val = fp[pix];
    }
    out[blk * 256 + t] = val;              // coalesced: consecutive t -> dwords
}

extern "C" void kernel_launch(void* const* d_in, const int* in_sizes, int n_in,
                              void* d_out, int out_size, void* d_ws, size_t ws_size,
                              hipStream_t stream) {
    const float* feat   = (const float*)d_in[0];  // [B,C,H,W] fp32
    const int*   labels = (const int*)d_in[1];    // [B,H,W] int32
    const float* preds  = (const float*)d_in[2];  // [B,NCLS,H,W] fp32
    float* out = (float*)d_out;

    // workspace layout (16B-aligned): ordered pixel buckets + band counts.
    // Poison-safe: bucket entries beyond the written count are never read.
    int* hardBuf = (int*)d_ws;                                  // 12*128*512 ints
    int* easyBuf = hardBuf + NPAIR * NBAND * BANDCAP;           // 12*128*512 ints
    unsigned* bandCounts = (unsigned*)(easyBuf + NPAIR * NBAND * BANDCAP); // 1536

    k_count<<<NBAND * BB, 256, 0, stream>>>(preds, labels, hardBuf, easyBuf, bandCounts);
    k_gather<<<NPAIR * CC * 4, 256, 0, stream>>>(feat, hardBuf, easyBuf, bandCounts, out);
}